// Round 8
// baseline (215.588 us; speedup 1.0000x reference)
//
#include <hip/hip_runtime.h>
#include <hip/hip_bf16.h>

#define NN 4096
#define KIN 256
#define HF 512
#define NHD 4
#define OF 128
#define JP 4160            // padded hbT row stride (8320 B: non-pow2 channel spread)

typedef __bf16 bf16x8 __attribute__((ext_vector_type(8)));
typedef __bf16 bf16x4 __attribute__((ext_vector_type(4)));
typedef float f32x4 __attribute__((ext_vector_type(4)));
typedef _Float16 f16x4 __attribute__((ext_vector_type(4)));

// ---------------- K0: WT[c][k] = (bf16)W[k][c], LDS-tiled ----------------
__global__ __launch_bounds__(256) void k_transpose_w(const float* __restrict__ W,
                                                     __bf16* __restrict__ WT) {
    __shared__ __bf16 tl[64][65];
    int k0 = blockIdx.x * 64, c0 = blockIdx.y * 64;
    #pragma unroll
    for (int it = 0; it < 16; ++it) {
        int idx = it * 256 + threadIdx.x;
        int kk = idx >> 6, cc = idx & 63;
        tl[kk][cc] = (__bf16)W[(size_t)(k0 + kk) * HF + c0 + cc];
    }
    __syncthreads();
    #pragma unroll
    for (int it = 0; it < 16; ++it) {
        int idx = it * 256 + threadIdx.x;
        int cc = idx >> 6, kk = idx & 63;
        WT[(size_t)(c0 + cc) * KIN + k0 + kk] = tl[kk][cc];
    }
}

// ------- K1: gemm (hbT) + fused ci/cj. grid (256 node-tiles, 4 h). -------
// Block = 256 thr = 4 waves, wave w: c0 = h*128+w*32. UNCHANGED this round
// (clean attribution); if it surfaces in top-5 once k_attn shrinks, its
// counters drive the next round.
__global__ __launch_bounds__(256) void k_gemm_h(const float* __restrict__ x,
                                                const __bf16* __restrict__ WT,
                                                const float* __restrict__ ai,
                                                const float* __restrict__ aj,
                                                __bf16* __restrict__ hbT,
                                                float* __restrict__ ci,
                                                float* __restrict__ cj) {
    __shared__ float credi[4][16], credj[4][16];
    int tid = threadIdx.x, lane = tid & 63, w = tid >> 6;
    int r = lane & 15, q = lane >> 4;
    int m0 = blockIdx.x * 16;
    int h = blockIdx.y;
    int c0 = h * 128 + w * 32;
    f32x4 acc[2];
    #pragma unroll
    for (int nt = 0; nt < 2; ++nt) acc[nt] = (f32x4){0.f, 0.f, 0.f, 0.f};
    const float* xp = x + (size_t)(m0 + r) * KIN + q * 8;
    #pragma unroll
    for (int kk = 0; kk < 8; ++kk) {
        float4 xa = *(const float4*)(xp + kk * 32);
        float4 xb = *(const float4*)(xp + kk * 32 + 4);
        bf16x8 af;
        af[0] = (__bf16)xa.x; af[1] = (__bf16)xa.y; af[2] = (__bf16)xa.z; af[3] = (__bf16)xa.w;
        af[4] = (__bf16)xb.x; af[5] = (__bf16)xb.y; af[6] = (__bf16)xb.z; af[7] = (__bf16)xb.w;
        #pragma unroll
        for (int nt = 0; nt < 2; ++nt) {
            bf16x8 bf = *(const bf16x8*)(WT + (size_t)(c0 + nt * 16 + r) * KIN + kk * 32 + q * 8);
            acc[nt] = __builtin_amdgcn_mfma_f32_16x16x32_bf16(af, bf, acc[nt], 0, 0, 0);
        }
    }
    float pi[4] = {0.f, 0.f, 0.f, 0.f}, pj[4] = {0.f, 0.f, 0.f, 0.f};
    #pragma unroll
    for (int nt = 0; nt < 2; ++nt) {
        int c = c0 + nt * 16 + r;
        float av = ai[c], jv = aj[c];
        bf16x4 o;
        #pragma unroll
        for (int e = 0; e < 4; ++e) {
            o[e] = (__bf16)acc[nt][e];
            pi[e] += av * acc[nt][e];
            pj[e] += jv * acc[nt][e];
        }
        *(bf16x4*)(hbT + (size_t)c * JP + m0 + q * 4) = o;
    }
    #pragma unroll
    for (int off = 1; off < 16; off <<= 1)
        #pragma unroll
        for (int e = 0; e < 4; ++e) {
            pi[e] += __shfl_xor(pi[e], off);
            pj[e] += __shfl_xor(pj[e], off);
        }
    if (r == 0)
        #pragma unroll
        for (int e = 0; e < 4; ++e) {
            credi[w][q * 4 + e] = pi[e];
            credj[w][q * 4 + e] = pj[e];
        }
    __syncthreads();
    if (tid < 16) {
        ci[h * NN + m0 + tid] = credi[0][tid] + credi[1][tid] + credi[2][tid] + credi[3][tid];
    } else if (tid >= 64 && tid < 80) {
        int nl = tid - 64;
        cj[h * NN + m0 + nl] = credj[0][nl] + credj[1][nl] + credj[2][nl] + credj[3][nl];
    }
}

// ---------------- K3: fused attention, zero LDS, PINNED 2 waves/EU ----------------
// ROUND-8: amdgpu_waves_per_eu(2,2). Round 7 proved launch_bounds(512,1) only
// sets the occupancy FLOOR; the backend still targeted 4 waves/EU and allocated
// 128 VGPRs (+minor spill). Pinning min=max=2 gives the allocator the full
// 256-VGPR budget so vb[2][8](64) + acc(64) + pa/pc(48) + af(16) + addr can all
// be register-resident -> the 16 V loads and 12 adj/cj prefetches actually stay
// in flight (designed MLP), instead of being re-serialized in 2-4-reg batches.
// jsn=4 -> grid 256 = 1 block/CU (ILP design point; 2/EU is all we need).
__global__ __attribute__((amdgpu_waves_per_eu(2, 2)))
__launch_bounds__(512) void k_attn(const float* __restrict__ adj,
                                   const __bf16* __restrict__ hbT,
                                   const float* __restrict__ ci,
                                   const float* __restrict__ cj,
                                   _Float16* __restrict__ num,
                                   float* __restrict__ den,
                                   int jmask, int jsh) {
    int tid = threadIdx.x, lane = tid & 63, w = tid >> 6;
    int h = w & 3, rg = w >> 2;
    int m = lane & 15, q = lane >> 4;
    int bid = blockIdx.x;
    int js = bid & jmask;
    int i0 = (bid >> jsh) << 6;
    int jb = js << (12 - jsh);          // slice width = NN >> jsh
    int nch = 1 << (6 - jsh);           // chunks of 64 j per slice

    // per-lane fragment base pointers
    const float* ap0 = adj + (size_t)(i0 + rg * 32 + m) * NN + jb + q * 8;       // g=0 row
    const float* ap1 = ap0 + (size_t)16 * NN;                                    // g=1 row
    const float* cjp = cj + (size_t)h * NN + jb + q * 8;
    const __bf16* vp = hbT + (size_t)(h * OF + m) * JP + jb + q * 8;

    float civ0 = ci[h * NN + i0 + rg * 32 + m];
    float civ1 = ci[h * NN + i0 + rg * 32 + 16 + m];

    f32x4 acc[2][8];
    #pragma unroll
    for (int g = 0; g < 2; ++g)
        #pragma unroll
        for (int nt = 0; nt < 8; ++nt) acc[g][nt] = (f32x4){0.f, 0.f, 0.f, 0.f};
    float den0 = 0.f, den1 = 0.f;

    // prefetch chunk 0: adj frags (8xfloat4) + cj frags (4xfloat4)
    // pa layout: [g*4 + ks*2 + half]
    float4 pa[8], pc[4];
    pa[0] = *(const float4*)(ap0);
    pa[1] = *(const float4*)(ap0 + 4);
    pa[2] = *(const float4*)(ap0 + 32);
    pa[3] = *(const float4*)(ap0 + 36);
    pa[4] = *(const float4*)(ap1);
    pa[5] = *(const float4*)(ap1 + 4);
    pa[6] = *(const float4*)(ap1 + 32);
    pa[7] = *(const float4*)(ap1 + 36);
    pc[0] = *(const float4*)(cjp);
    pc[1] = *(const float4*)(cjp + 4);
    pc[2] = *(const float4*)(cjp + 32);
    pc[3] = *(const float4*)(cjp + 36);

    for (int c = 0; c < nch; ++c) {
        // ---- 1. issue ALL V loads for this chunk (independent, MLP=16) ----
        bf16x8 vb[2][8];
        #pragma unroll
        for (int ks = 0; ks < 2; ++ks)
            #pragma unroll
            for (int nt = 0; nt < 8; ++nt)
                vb[ks][nt] = *(const bf16x8*)(vp + (size_t)(nt * 16) * JP + c * 64 + ks * 32);

        bf16x8 af0[2], af1[2];
        int off = (c + 1) * 64;

        // ---- 2. VALU ks=0 (covers V latency), then re-issue its adj/cj regs ----
        {
            float ccv[8];
            ccv[0] = pc[0].x; ccv[1] = pc[0].y; ccv[2] = pc[0].z; ccv[3] = pc[0].w;
            ccv[4] = pc[1].x; ccv[5] = pc[1].y; ccv[6] = pc[1].z; ccv[7] = pc[1].w;
            float aa0[8], aa1[8];
            aa0[0] = pa[0].x; aa0[1] = pa[0].y; aa0[2] = pa[0].z; aa0[3] = pa[0].w;
            aa0[4] = pa[1].x; aa0[5] = pa[1].y; aa0[6] = pa[1].z; aa0[7] = pa[1].w;
            aa1[0] = pa[4].x; aa1[1] = pa[4].y; aa1[2] = pa[4].z; aa1[3] = pa[4].w;
            aa1[4] = pa[5].x; aa1[5] = pa[5].y; aa1[6] = pa[5].z; aa1[7] = pa[5].w;
            #pragma unroll
            for (int u = 0; u < 8; ++u) {
                float a = aa0[u];
                float s = civ0 + ccv[u];
                s = fmaxf(s, s * 0.2f);     // leaky_relu
                s *= a;
                float p = __expf(s);        // s in ~[-4,4]: shift-free softmax safe
                den0 += p;
                af0[0][u] = (__bf16)(p * a);
            }
            #pragma unroll
            for (int u = 0; u < 8; ++u) {
                float a = aa1[u];
                float s = civ1 + ccv[u];
                s = fmaxf(s, s * 0.2f);
                s *= a;
                float p = __expf(s);
                den1 += p;
                af1[0][u] = (__bf16)(p * a);
            }
        }
        if (c + 1 < nch) {                  // prefetch the regs ks=0 just freed
            pa[0] = *(const float4*)(ap0 + off);
            pa[1] = *(const float4*)(ap0 + off + 4);
            pa[4] = *(const float4*)(ap1 + off);
            pa[5] = *(const float4*)(ap1 + off + 4);
            pc[0] = *(const float4*)(cjp + off);
            pc[1] = *(const float4*)(cjp + off + 4);
        }

        // ---- 3. VALU ks=1, then re-issue its adj/cj regs ----
        {
            float ccv[8];
            ccv[0] = pc[2].x; ccv[1] = pc[2].y; ccv[2] = pc[2].z; ccv[3] = pc[2].w;
            ccv[4] = pc[3].x; ccv[5] = pc[3].y; ccv[6] = pc[3].z; ccv[7] = pc[3].w;
            float aa0[8], aa1[8];
            aa0[0] = pa[2].x; aa0[1] = pa[2].y; aa0[2] = pa[2].z; aa0[3] = pa[2].w;
            aa0[4] = pa[3].x; aa0[5] = pa[3].y; aa0[6] = pa[3].z; aa0[7] = pa[3].w;
            aa1[0] = pa[6].x; aa1[1] = pa[6].y; aa1[2] = pa[6].z; aa1[3] = pa[6].w;
            aa1[4] = pa[7].x; aa1[5] = pa[7].y; aa1[6] = pa[7].z; aa1[7] = pa[7].w;
            #pragma unroll
            for (int u = 0; u < 8; ++u) {
                float a = aa0[u];
                float s = civ0 + ccv[u];
                s = fmaxf(s, s * 0.2f);
                s *= a;
                float p = __expf(s);
                den0 += p;
                af0[1][u] = (__bf16)(p * a);
            }
            #pragma unroll
            for (int u = 0; u < 8; ++u) {
                float a = aa1[u];
                float s = civ1 + ccv[u];
                s = fmaxf(s, s * 0.2f);
                s *= a;
                float p = __expf(s);
                den1 += p;
                af1[1][u] = (__bf16)(p * a);
            }
        }
        if (c + 1 < nch) {
            pa[2] = *(const float4*)(ap0 + off + 32);
            pa[3] = *(const float4*)(ap0 + off + 36);
            pa[6] = *(const float4*)(ap1 + off + 32);
            pa[7] = *(const float4*)(ap1 + off + 36);
            pc[2] = *(const float4*)(cjp + off + 32);
            pc[3] = *(const float4*)(cjp + off + 36);
        }

        // ---- 4. MFMA phase: V fragments already in vb registers ----
        #pragma unroll
        for (int ks = 0; ks < 2; ++ks)
            #pragma unroll
            for (int nt = 0; nt < 8; ++nt) {
                acc[0][nt] = __builtin_amdgcn_mfma_f32_16x16x32_bf16(af0[ks], vb[ks][nt], acc[0][nt], 0, 0, 0);
                acc[1][nt] = __builtin_amdgcn_mfma_f32_16x16x32_bf16(af1[ks], vb[ks][nt], acc[1][nt], 0, 0, 0);
            }
    }
    // den over q-partitions (j mod 32): lanes {m, m+16, m+32, m+48}
    den0 += __shfl_xor(den0, 16); den0 += __shfl_xor(den0, 32);
    den1 += __shfl_xor(den1, 16); den1 += __shfl_xor(den1, 32);
    if (lane < 16) {
        float* dp = den + ((size_t)js * NHD + h) * NN + i0 + rg * 32;
        dp[lane] = den0;
        dp[16 + lane] = den1;
    }
    // num partials (fp16): C/D row = q*4+reg (i-local), col = nt*16+m (f)
    #pragma unroll
    for (int g = 0; g < 2; ++g)
        #pragma unroll
        for (int nt = 0; nt < 8; ++nt)
            #pragma unroll
            for (int reg = 0; reg < 4; ++reg) {
                int i = i0 + rg * 32 + g * 16 + q * 4 + reg;
                num[((size_t)js * NN + i) * HF + h * OF + nt * 16 + m] =
                    (_Float16)acc[g][nt][reg];
            }
}

// ---------------- K4: reduce jsn partials, divide, +bias, fp32 out ---------
__global__ __launch_bounds__(256) void k_reduce(const _Float16* __restrict__ num,
                                               const float* __restrict__ den,
                                               const float* __restrict__ bias,
                                               float* __restrict__ out,
                                               int jsn) {
    int g = blockIdx.x * 256 + threadIdx.x;    // NN*HF/4 groups
    int i = g >> 7, c4 = (g & 127) << 2;
    int h = c4 >> 7;
    float s0 = 0.f, s1 = 0.f, s2 = 0.f, s3 = 0.f, d = 0.f;
    for (int js = 0; js < jsn; ++js) {
        f16x4 v = *(const f16x4*)(num + ((size_t)js * NN + i) * HF + c4);
        s0 += (float)v[0]; s1 += (float)v[1]; s2 += (float)v[2]; s3 += (float)v[3];
        d += den[((size_t)js * NHD + h) * NN + i];
    }
    float inv = 1.0f / d;
    float4 b = *(const float4*)(bias + c4);
    float4 o;
    o.x = s0 * inv + b.x; o.y = s1 * inv + b.y;
    o.z = s2 * inv + b.z; o.w = s3 * inv + b.w;
    *(float4*)(out + (size_t)i * HF + c4) = o;
}

extern "C" void kernel_launch(void* const* d_in, const int* in_sizes, int n_in,
                              void* d_out, int out_size, void* d_ws, size_t ws_size,
                              hipStream_t stream) {
    const float* x    = (const float*)d_in[0];
    const float* adj  = (const float*)d_in[1];
    const float* W    = (const float*)d_in[2];
    const float* ai   = (const float*)d_in[3];
    const float* aj   = (const float*)d_in[4];
    const float* bias = (const float*)d_in[5];
    float* out = (float*)d_out;

    int jsn = 4, jsh = 2;   // grid 256 = 1 block/CU at full register budget

    char* ws = (char*)d_ws;
    __bf16*   hbT = (__bf16*)(ws);                               // 4,259,840 B used
    float*    ci  = (float*)(ws + 4456448);                      // 64 KB
    float*    cj  = (float*)(ws + 4521984);                      // 64 KB
    __bf16*   WT  = (__bf16*)(ws + 4587520);                     // 256 KB
    float*    den = (float*)(ws + 4849664);                      // jsn*64 KB
    _Float16* num = (_Float16*)(ws + 4849664 + (size_t)jsn * 65536);  // jsn*4 MB

    k_transpose_w<<<dim3(4, 8), 256, 0, stream>>>(W, WT);
    k_gemm_h<<<dim3(256, 4), 256, 0, stream>>>(x, WT, ai, aj, hbT, ci, cj);
    k_attn<<<jsn * 64, 512, 0, stream>>>(adj, hbT, ci, cj, num, den, jsn - 1, jsh);
    k_reduce<<<2048, 256, 0, stream>>>(num, den, bias, out, jsn);
}

// Round 9
// 187.660 us; speedup vs baseline: 1.1488x; 1.1488x over previous
//
#include <hip/hip_runtime.h>
#include <hip/hip_bf16.h>

#define NN 4096
#define KIN 256
#define HF 512
#define NHD 4
#define OF 128
#define JP 4160            // padded hbT row stride (8320 B: non-pow2 channel spread)

typedef __bf16 bf16x8 __attribute__((ext_vector_type(8)));
typedef __bf16 bf16x4 __attribute__((ext_vector_type(4)));
typedef float f32x4 __attribute__((ext_vector_type(4)));
typedef _Float16 f16x4 __attribute__((ext_vector_type(4)));

// async 16B/lane global->LDS: dest = wave-uniform LDS base + lane*16,
// src = per-lane global address. In-flight state lives in the vmem queue,
// NOT in VGPRs (the 128-reg allocator cap made reg-based MLP impossible).
__device__ __forceinline__ void glds16(const void* g, void* l) {
    __builtin_amdgcn_global_load_lds(
        (const __attribute__((address_space(1))) void*)g,
        (__attribute__((address_space(3))) void*)l, 16, 0, 0);
}

// ---------------- K0: WT[c][k] = (bf16)W[k][c], LDS-tiled ----------------
__global__ __launch_bounds__(256) void k_transpose_w(const float* __restrict__ W,
                                                     __bf16* __restrict__ WT) {
    __shared__ __bf16 tl[64][65];
    int k0 = blockIdx.x * 64, c0 = blockIdx.y * 64;
    #pragma unroll
    for (int it = 0; it < 16; ++it) {
        int idx = it * 256 + threadIdx.x;
        int kk = idx >> 6, cc = idx & 63;
        tl[kk][cc] = (__bf16)W[(size_t)(k0 + kk) * HF + c0 + cc];
    }
    __syncthreads();
    #pragma unroll
    for (int it = 0; it < 16; ++it) {
        int idx = it * 256 + threadIdx.x;
        int cc = idx >> 6, kk = idx & 63;
        WT[(size_t)(c0 + cc) * KIN + k0 + kk] = tl[kk][cc];
    }
}

// ------- K1: gemm (hbT) + fused ci/cj. grid (256 node-tiles, 4 h). -------
// UNCHANGED this round (clean attribution for the k_attn rewrite).
__global__ __launch_bounds__(256) void k_gemm_h(const float* __restrict__ x,
                                                const __bf16* __restrict__ WT,
                                                const float* __restrict__ ai,
                                                const float* __restrict__ aj,
                                                __bf16* __restrict__ hbT,
                                                float* __restrict__ ci,
                                                float* __restrict__ cj) {
    __shared__ float credi[4][16], credj[4][16];
    int tid = threadIdx.x, lane = tid & 63, w = tid >> 6;
    int r = lane & 15, q = lane >> 4;
    int m0 = blockIdx.x * 16;
    int h = blockIdx.y;
    int c0 = h * 128 + w * 32;
    f32x4 acc[2];
    #pragma unroll
    for (int nt = 0; nt < 2; ++nt) acc[nt] = (f32x4){0.f, 0.f, 0.f, 0.f};
    const float* xp = x + (size_t)(m0 + r) * KIN + q * 8;
    #pragma unroll
    for (int kk = 0; kk < 8; ++kk) {
        float4 xa = *(const float4*)(xp + kk * 32);
        float4 xb = *(const float4*)(xp + kk * 32 + 4);
        bf16x8 af;
        af[0] = (__bf16)xa.x; af[1] = (__bf16)xa.y; af[2] = (__bf16)xa.z; af[3] = (__bf16)xa.w;
        af[4] = (__bf16)xb.x; af[5] = (__bf16)xb.y; af[6] = (__bf16)xb.z; af[7] = (__bf16)xb.w;
        #pragma unroll
        for (int nt = 0; nt < 2; ++nt) {
            bf16x8 bf = *(const bf16x8*)(WT + (size_t)(c0 + nt * 16 + r) * KIN + kk * 32 + q * 8);
            acc[nt] = __builtin_amdgcn_mfma_f32_16x16x32_bf16(af, bf, acc[nt], 0, 0, 0);
        }
    }
    float pi[4] = {0.f, 0.f, 0.f, 0.f}, pj[4] = {0.f, 0.f, 0.f, 0.f};
    #pragma unroll
    for (int nt = 0; nt < 2; ++nt) {
        int c = c0 + nt * 16 + r;
        float av = ai[c], jv = aj[c];
        bf16x4 o;
        #pragma unroll
        for (int e = 0; e < 4; ++e) {
            o[e] = (__bf16)acc[nt][e];
            pi[e] += av * acc[nt][e];
            pj[e] += jv * acc[nt][e];
        }
        *(bf16x4*)(hbT + (size_t)c * JP + m0 + q * 4) = o;
    }
    #pragma unroll
    for (int off = 1; off < 16; off <<= 1)
        #pragma unroll
        for (int e = 0; e < 4; ++e) {
            pi[e] += __shfl_xor(pi[e], off);
            pj[e] += __shfl_xor(pj[e], off);
        }
    if (r == 0)
        #pragma unroll
        for (int e = 0; e < 4; ++e) {
            credi[w][q * 4 + e] = pi[e];
            credj[w][q * 4 + e] = pj[e];
        }
    __syncthreads();
    if (tid < 16) {
        ci[h * NN + m0 + tid] = credi[0][tid] + credi[1][tid] + credi[2][tid] + credi[3][tid];
    } else if (tid >= 64 && tid < 80) {
        int nl = tid - 64;
        cj[h * NN + m0 + nl] = credj[0][nl] + credj[1][nl] + credj[2][nl] + credj[3][nl];
    }
}

// ---------------- K3: fused attention, async LDS pipeline ----------------
// ROUND-9 REWRITE: the in-flight memory state moves from VGPRs (allocator-
// capped at 128 for 4 rounds) into the global_load_lds queue + LDS.
//   - 32-j chunks, double-buffered: V [512][32]bf16 (64KB dbuf) + adj
//     [64][32]f32 (16KB dbuf) = 80KB -> 1 block/CU.
//   - per chunk per wave: 5 glds16 (4 V + 1 adj, each a contiguous 1KB
//     wave-block = 8 sequential cache lines, vs 28 divergent fragment loads
//     touching ~390 lines before) issued for c+1 BEFORE computing c.
//   - counted vmcnt(7): stage(c+1)5 + cj(c+1)2 stay in flight across the
//     barrier; never a full drain in the loop (T4).
//   - raw s_barrier builtins + "" memory-clobber asm fences pin the order
//     (no __syncthreads -> no compiler vmcnt(0) drain).
//   - bank swizzle (rule #21, both sides): adj 16B-slot ^= (row&7) -> 2-way
//     (free); V slot ^= (row&3) -> 4-way (1.58x, ~40cy/wave). Staging
//     SOURCE addresses pre-swizzled to match; LDS dest stays linear.
__global__ __launch_bounds__(512) void k_attn(const float* __restrict__ adj,
                                              const __bf16* __restrict__ hbT,
                                              const float* __restrict__ ci,
                                              const float* __restrict__ cj,
                                              _Float16* __restrict__ num,
                                              float* __restrict__ den,
                                              int jmask, int jsh) {
    __shared__ __bf16 vt[2][512][32];    // [buf][h*128+ch][j-slot swizzled]
    __shared__ float  ats[2][64][32];    // [buf][i-local][j-slot swizzled]
    int tid = threadIdx.x, lane = tid & 63, w = tid >> 6;
    int h = w & 3, rg = w >> 2;
    int m = lane & 15, q = lane >> 4;
    int bid = blockIdx.x;
    int js = bid & jmask;
    int i0 = (bid >> jsh) << 6;
    int jb = js << (12 - jsh);          // slice width = NN >> jsh (=1024)
    int nch = 1 << (7 - jsh);           // chunks of 32 j per slice (=32)

    // ---- staging source pointers (per-lane, chunk 0; advance by 32 elems/chunk)
    // V: wave w stages rows (w*4+k)*16 .. +15 (k=0..3), 1KB per inst.
    //    lane -> row t = base + (lane>>2), phys slot = lane&3,
    //    source j-slot = (lane&3) ^ (t&3)  (inverse swizzle).
    const __bf16* vS[4];
    int tS[4];
    #pragma unroll
    for (int k = 0; k < 4; ++k) {
        int t = (w * 4 + k) * 16 + (lane >> 2);
        tS[k] = t;
        vS[k] = hbT + (size_t)t * JP + jb + (((lane & 3) ^ (t & 3)) * 8);
    }
    // adj: wave w stages rows w*8 .. w*8+7. lane -> row il = w*8 + (lane>>3),
    //      phys slot = lane&7, source j-slot = (lane&7) ^ (il&7).
    int il = w * 8 + (lane >> 3);
    const float* aS = adj + (size_t)(i0 + il) * NN + jb + (((lane & 7) ^ (il & 7)) * 4);
    // cj: register prefetch (wave-shared row, L1-friendly; never the problem)
    const float* cjsrc = cj + (size_t)h * NN + jb + q * 8;

    float civ0 = ci[h * NN + i0 + rg * 32 + m];
    float civ1 = ci[h * NN + i0 + rg * 32 + 16 + m];

    f32x4 acc[2][8];
    #pragma unroll
    for (int g = 0; g < 2; ++g)
        #pragma unroll
        for (int nt = 0; nt < 8; ++nt) acc[g][nt] = (f32x4){0.f, 0.f, 0.f, 0.f};
    float den0 = 0.f, den1 = 0.f;

    // ---- prologue: stage chunk 0 into buf 0; prefetch cj chunk 0 ----
    #pragma unroll
    for (int k = 0; k < 4; ++k) glds16(vS[k], &vt[0][(w * 4 + k) * 16][0]);
    glds16(aS, &ats[0][w * 8][0]);
    float4 pc0 = *(const float4*)(cjsrc);
    float4 pc1 = *(const float4*)(cjsrc + 4);

    int ir0 = rg * 32 + m;              // g=0 LDS adj row; g=1 is +16
    int sA0 = ((2 * q + 0) ^ (m & 7)) * 4;   // adj phys slot offsets (floats)
    int sA1 = ((2 * q + 1) ^ (m & 7)) * 4;
    int sV  = (q ^ (m & 3)) * 8;             // V phys slot offset (bf16)

    for (int c = 0; c < nch; ++c) {
        int cb = c & 1, nb = cb ^ 1;
        // ---- issue next-chunk staging, then counted wait for THIS chunk ----
        if (c + 1 < nch) {
            #pragma unroll
            for (int k = 0; k < 4; ++k)
                glds16(vS[k] + (size_t)(c + 1) * 32, &vt[nb][(w * 4 + k) * 16][0]);
            glds16(aS + (size_t)(c + 1) * 32, &ats[nb][w * 8][0]);
            asm volatile("s_waitcnt vmcnt(7)" ::: "memory");   // 5 stage + 2 cj stay in flight
        } else {
            asm volatile("s_waitcnt vmcnt(0)" ::: "memory");   // tail drain (once)
        }
        __builtin_amdgcn_s_barrier();                          // buf[cb] fully staged
        asm volatile("" ::: "memory");                         // no ds_read hoists above

        // ---- adj fragments from LDS (2-way = free) ----
        float4 x00 = *(const float4*)&ats[cb][ir0][sA0];
        float4 x01 = *(const float4*)&ats[cb][ir0][sA1];
        float4 x10 = *(const float4*)&ats[cb][ir0 + 16][sA0];
        float4 x11 = *(const float4*)&ats[cb][ir0 + 16][sA1];
        float ccv[8];
        ccv[0] = pc0.x; ccv[1] = pc0.y; ccv[2] = pc0.z; ccv[3] = pc0.w;
        ccv[4] = pc1.x; ccv[5] = pc1.y; ccv[6] = pc1.z; ccv[7] = pc1.w;
        float aa0[8], aa1[8];
        aa0[0] = x00.x; aa0[1] = x00.y; aa0[2] = x00.z; aa0[3] = x00.w;
        aa0[4] = x01.x; aa0[5] = x01.y; aa0[6] = x01.z; aa0[7] = x01.w;
        aa1[0] = x10.x; aa1[1] = x10.y; aa1[2] = x10.z; aa1[3] = x10.w;
        aa1[4] = x11.x; aa1[5] = x11.y; aa1[6] = x11.z; aa1[7] = x11.w;

        bf16x8 af0, af1;
        #pragma unroll
        for (int u = 0; u < 8; ++u) {
            float a = aa0[u];
            float s = civ0 + ccv[u];
            s = fmaxf(s, s * 0.2f);     // leaky_relu
            s *= a;
            float p = __expf(s);        // s in ~[-4,4]: shift-free softmax safe
            den0 += p;
            af0[u] = (__bf16)(p * a);
        }
        #pragma unroll
        for (int u = 0; u < 8; ++u) {
            float a = aa1[u];
            float s = civ1 + ccv[u];
            s = fmaxf(s, s * 0.2f);
            s *= a;
            float p = __expf(s);
            den1 += p;
            af1[u] = (__bf16)(p * a);
        }
        // cj prefetch for next chunk (pc consumed above)
        if (c + 1 < nch) {
            pc0 = *(const float4*)(cjsrc + (c + 1) * 32);
            pc1 = *(const float4*)(cjsrc + (c + 1) * 32 + 4);
        }
        // ---- MFMA: V fragments from LDS (4-way, 1.58x — negligible) ----
        #pragma unroll
        for (int nt = 0; nt < 8; ++nt) {
            bf16x8 bfv = *(const bf16x8*)&vt[cb][h * 128 + nt * 16 + m][sV];
            acc[0][nt] = __builtin_amdgcn_mfma_f32_16x16x32_bf16(af0, bfv, acc[0][nt], 0, 0, 0);
            acc[1][nt] = __builtin_amdgcn_mfma_f32_16x16x32_bf16(af1, bfv, acc[1][nt], 0, 0, 0);
        }
        asm volatile("" ::: "memory");                         // no ds_read sinks below
        __builtin_amdgcn_s_barrier();                          // all done with buf[cb]
    }
    // den over q-partitions (j mod 32): lanes {m, m+16, m+32, m+48}
    den0 += __shfl_xor(den0, 16); den0 += __shfl_xor(den0, 32);
    den1 += __shfl_xor(den1, 16); den1 += __shfl_xor(den1, 32);
    if (lane < 16) {
        float* dp = den + ((size_t)js * NHD + h) * NN + i0 + rg * 32;
        dp[lane] = den0;
        dp[16 + lane] = den1;
    }
    // num partials (fp16): C/D row = q*4+reg (i-local), col = nt*16+m (f)
    #pragma unroll
    for (int g = 0; g < 2; ++g)
        #pragma unroll
        for (int nt = 0; nt < 8; ++nt)
            #pragma unroll
            for (int reg = 0; reg < 4; ++reg) {
                int i = i0 + rg * 32 + g * 16 + q * 4 + reg;
                num[((size_t)js * NN + i) * HF + h * OF + nt * 16 + m] =
                    (_Float16)acc[g][nt][reg];
            }
}

// ---------------- K4: reduce jsn partials, divide, +bias, fp32 out ---------
__global__ __launch_bounds__(256) void k_reduce(const _Float16* __restrict__ num,
                                               const float* __restrict__ den,
                                               const float* __restrict__ bias,
                                               float* __restrict__ out,
                                               int jsn) {
    int g = blockIdx.x * 256 + threadIdx.x;    // NN*HF/4 groups
    int i = g >> 7, c4 = (g & 127) << 2;
    int h = c4 >> 7;
    float s0 = 0.f, s1 = 0.f, s2 = 0.f, s3 = 0.f, d = 0.f;
    for (int js = 0; js < jsn; ++js) {
        f16x4 v = *(const f16x4*)(num + ((size_t)js * NN + i) * HF + c4);
        s0 += (float)v[0]; s1 += (float)v[1]; s2 += (float)v[2]; s3 += (float)v[3];
        d += den[((size_t)js * NHD + h) * NN + i];
    }
    float inv = 1.0f / d;
    float4 b = *(const float4*)(bias + c4);
    float4 o;
    o.x = s0 * inv + b.x; o.y = s1 * inv + b.y;
    o.z = s2 * inv + b.z; o.w = s3 * inv + b.w;
    *(float4*)(out + (size_t)i * HF + c4) = o;
}

extern "C" void kernel_launch(void* const* d_in, const int* in_sizes, int n_in,
                              void* d_out, int out_size, void* d_ws, size_t ws_size,
                              hipStream_t stream) {
    const float* x    = (const float*)d_in[0];
    const float* adj  = (const float*)d_in[1];
    const float* W    = (const float*)d_in[2];
    const float* ai   = (const float*)d_in[3];
    const float* aj   = (const float*)d_in[4];
    const float* bias = (const float*)d_in[5];
    float* out = (float*)d_out;

    int jsn = 4, jsh = 2;   // grid 256 = 1 block/CU (LDS-forced anyway)

    char* ws = (char*)d_ws;
    __bf16*   hbT = (__bf16*)(ws);                               // 4,259,840 B used
    float*    ci  = (float*)(ws + 4456448);                      // 64 KB
    float*    cj  = (float*)(ws + 4521984);                      // 64 KB
    __bf16*   WT  = (__bf16*)(ws + 4587520);                     // 256 KB
    float*    den = (float*)(ws + 4849664);                      // jsn*64 KB
    _Float16* num = (_Float16*)(ws + 4849664 + (size_t)jsn * 65536);  // jsn*4 MB

    k_transpose_w<<<dim3(4, 8), 256, 0, stream>>>(W, WT);
    k_gemm_h<<<dim3(256, 4), 256, 0, stream>>>(x, WT, ai, aj, hbT, ci, cj);
    k_attn<<<jsn * 64, 512, 0, stream>>>(adj, hbT, ci, cj, num, den, jsn - 1, jsh);
    k_reduce<<<2048, 256, 0, stream>>>(num, den, bias, out, jsn);
}